// Round 3
// baseline (2042.543 us; speedup 1.0000x reference)
//
#include <hip/hip_runtime.h>

// GatedSpatialLinearAttention on MI355X (gfx950).
// Round 3: split-bf16 (hi+lo) 3-pass MFMA emulation of fp32 GEMMs.
//   A*B ~= Ah*Bh + Ah*Bl + Al*Bh  (f32 accum; dropped Al*Bl ~ 2^-18 rel)
// q,g stored f32; k,v,att stored as bf16 hi/lo pairs; all softmax/attention
// arithmetic in f32. elu(softmax)+1 == softmax+1; "+1" carried analytically.
// Workspace adaptive: chunk over bf. per-bf 28.5MB + 2.5MB fixed.

typedef unsigned short u16;
typedef unsigned int u32;
typedef __bf16 bf16x8 __attribute__((ext_vector_type(8)));
typedef float f32x4 __attribute__((ext_vector_type(4)));

__device__ inline float bf2f(u16 v) { union { u32 i; float f; } u; u.i = ((u32)v) << 16; return u.f; }
__device__ inline u16 f2bf(float f) {
    union { float f; u32 i; } u; u.f = f;
    u32 r = (u.i + 0x7fffu + ((u.i >> 16) & 1u)) >> 16;   // RNE
    return (u16)r;
}
__device__ inline void split2(float v, u16& h, u16& l) {
    h = f2bf(v);
    l = f2bf(v - bf2f(h));
}

// ------------------------------------------------- cvt weights to hi/lo pairs
__global__ void k_cvt_w(const float* __restrict__ Wq, const float* __restrict__ Wk,
                        const float* __restrict__ Wv, const float* __restrict__ Wg,
                        const float* __restrict__ Wo,
                        u16* __restrict__ Wh, u16* __restrict__ Wl,
                        u16* __restrict__ Woh, u16* __restrict__ Wol)
{
    int idx = blockIdx.x * 256 + threadIdx.x;
    if (idx < 524288) {                       // W_all[2048][256] = [q;k;v;g]
        int o = idx >> 8, c = idx & 255;
        int which = o >> 9, r = o & 511;
        const float* s = (which == 0) ? Wq : (which == 1) ? Wk : (which == 2) ? Wv : Wg;
        u16 h, l; split2(s[r * 256 + c], h, l);
        Wh[idx] = h; Wl[idx] = l;
    } else {
        int j = idx - 524288;                 // Wo[256][512]
        if (j < 131072) { u16 h, l; split2(Wo[j], h, l); Woh[j] = h; Wol[j] = l; }
    }
}

// ----------------------- cvt x -> xh/xl [bf_local][n][c] bf16 pairs (chunked)
__global__ __launch_bounds__(256) void k_cvt_x(const float* __restrict__ x,
                                               u16* __restrict__ xh, u16* __restrict__ xl,
                                               int c0)
{
    __shared__ __align__(16) u16 tileh[64 * 132];   // [n_local][c_local], pad 132
    __shared__ __align__(16) u16 tilel[64 * 132];
    const int t = threadIdx.x;
    const int bfl = blockIdx.y;
    const int bfg = c0 + bfl;
    const int n0 = blockIdx.x * 128;
    const int b_ = bfg >> 4, f_ = bfg & 15;
    for (int s = 0; s < 2; ++s) {                   // n-half (64 px)
        for (int ch2 = 0; ch2 < 2; ++ch2) {         // c-half (128 ch)
            __syncthreads();
            for (int p = 0; p < 8; ++p) {
                int cl = p * 16 + (t >> 4);
                int c = ch2 * 128 + cl;
                const float* sp = x + (((size_t)b_ * 256 + c) * 16 + f_) * 4096
                                    + n0 + s * 64 + (t & 15) * 4;
                float4 v = *(const float4*)sp;
                float vv[4] = { v.x, v.y, v.z, v.w };
#pragma unroll
                for (int j = 0; j < 4; ++j) {
                    int nl = (t & 15) * 4 + j;
                    u16 h, l; split2(vv[j], h, l);
                    tileh[nl * 132 + cl] = h;
                    tilel[nl * 132 + cl] = l;
                }
            }
            __syncthreads();
#pragma unroll
            for (int i = 0; i < 4; ++i) {
                int flat = t + i * 256;             // 64n x 16 groups-of-8c
                int nn = flat >> 4, cc = flat & 15;
                size_t off = ((size_t)bfl * 4096 + n0 + s * 64 + nn) * 256 + ch2 * 128 + cc * 8;
                *(uint4*)(xh + off) = *(const uint4*)(tileh + nn * 132 + cc * 8);
                *(uint4*)(xl + off) = *(const uint4*)(tilel + nn * 132 + cc * 8);
            }
        }
    }
}

// ------------------------------------------------------- fused projection pass
// pass 0: k(512..1023)->kh/kl softmax-w, v(1024..1535)->vh/vl raw
// pass 1: q(0..511)->qf f32 raw, g(1536..2047)->gf f32 sigmoid(+bg)
__global__ __launch_bounds__(256) void k_proj(
    const u16* __restrict__ Wh, const u16* __restrict__ Wl,
    const u16* __restrict__ xh, const u16* __restrict__ xl,
    const float* __restrict__ bg,
    u16* __restrict__ kh, u16* __restrict__ kl,
    u16* __restrict__ vh, u16* __restrict__ vl,
    float* __restrict__ qf, float* __restrict__ gf, int pass)
{
    __shared__ __align__(16) char smem[65536];
    u16* Ah = (u16*)smem;                 // [128][64] each, XOR-swizzled
    u16* Al = (u16*)(smem + 16384);
    u16* Bh = (u16*)(smem + 32768);
    u16* Bl = (u16*)(smem + 49152);
    float* Csh = (float*)smem;            // [128][69] f32, reused after K loop
    const int t = threadIdx.x;
    const int bfl = blockIdx.z;
    const int by = blockIdx.y;
    const int m0 = (pass == 0) ? (512 + by * 128)
                               : ((by < 4) ? by * 128 : 1536 + (by - 4) * 128);
    const int n0 = blockIdx.x * 128;
    const int lane = t & 63, wv = t >> 6, wm = wv >> 1, wn = wv & 1;
    f32x4 acc[4][4] = {};
    const u16* Aph = Wh + (size_t)m0 * 256;
    const u16* Apl = Wl + (size_t)m0 * 256;
    const u16* Bph = xh + ((size_t)bfl * 4096 + n0) * 256;
    const u16* Bpl = xl + ((size_t)bfl * 4096 + n0) * 256;
    const int srow = t >> 3, sci = t & 7;

    for (int kt = 0; kt < 4; ++kt) {
        const int k0 = kt * 64;
#pragma unroll
        for (int p = 0; p < 4; ++p) {
            int row = srow + p * 32;
            size_t go = (size_t)row * 256 + k0 + sci * 8;
            int sc = (sci ^ (row & 7)) * 8;
            *(uint4*)(Ah + row * 64 + sc) = *(const uint4*)(Aph + go);
            *(uint4*)(Al + row * 64 + sc) = *(const uint4*)(Apl + go);
            *(uint4*)(Bh + row * 64 + sc) = *(const uint4*)(Bph + go);
            *(uint4*)(Bl + row * 64 + sc) = *(const uint4*)(Bpl + go);
        }
        __syncthreads();
#pragma unroll
        for (int kk = 0; kk < 2; ++kk) {
            bf16x8 afh[4], afl[4], bfh[4], bfl_[4];
#pragma unroll
            for (int i = 0; i < 4; ++i) {
                int ra = wm * 64 + i * 16 + (lane & 15);
                int ca = ((kk * 4 + (lane >> 4)) ^ (ra & 7)) * 8;
                afh[i] = *(const bf16x8*)(Ah + ra * 64 + ca);
                afl[i] = *(const bf16x8*)(Al + ra * 64 + ca);
                int rb = wn * 64 + i * 16 + (lane & 15);
                int cb = ((kk * 4 + (lane >> 4)) ^ (rb & 7)) * 8;
                bfh[i] = *(const bf16x8*)(Bh + rb * 64 + cb);
                bfl_[i] = *(const bf16x8*)(Bl + rb * 64 + cb);
            }
#pragma unroll
            for (int mi = 0; mi < 4; ++mi)
#pragma unroll
                for (int ni = 0; ni < 4; ++ni) {
                    acc[mi][ni] = __builtin_amdgcn_mfma_f32_16x16x32_bf16(afh[mi], bfh[ni], acc[mi][ni], 0, 0, 0);
                    acc[mi][ni] = __builtin_amdgcn_mfma_f32_16x16x32_bf16(afh[mi], bfl_[ni], acc[mi][ni], 0, 0, 0);
                    acc[mi][ni] = __builtin_amdgcn_mfma_f32_16x16x32_bf16(afl[mi], bfh[ni], acc[mi][ni], 0, 0, 0);
                }
        }
        __syncthreads();
    }

    const int sector = m0 >> 9;               // 0:q 1:k 2:v 3:g
    // Two n-phases: waves with wn==ph dump their 128x64 half into Csh f32,
    // then threads 0..127 each own one w-row of 64 px.
    for (int ph = 0; ph < 2; ++ph) {
        if (wn == ph) {
#pragma unroll
            for (int mi = 0; mi < 4; ++mi)
#pragma unroll
                for (int ni = 0; ni < 4; ++ni)
#pragma unroll
                    for (int r = 0; r < 4; ++r) {
                        int gr = wm * 64 + mi * 16 + (lane >> 4) * 4 + r;
                        int gcl = ni * 16 + (lane & 15);
                        Csh[gr * 69 + gcl] = acc[mi][ni][r];
                    }
        }
        __syncthreads();
        if (t < 128) {
            const float* src = Csh + t * 69;
            const int oloc = (m0 & 511) + t;
            const size_t doff = ((size_t)bfl * 512 + oloc) * 4096 + n0 + ph * 64;
            if (sector == 0) {                // q raw f32
#pragma unroll
                for (int i = 0; i < 16; ++i) {
                    float4 o = { src[i * 4], src[i * 4 + 1], src[i * 4 + 2], src[i * 4 + 3] };
                    *(float4*)(qf + doff + i * 4) = o;
                }
            } else if (sector == 2) {         // v split pair
#pragma unroll
                for (int i = 0; i < 8; ++i) {
                    union { u16 h[8]; uint4 u; } ph_, pl_;
#pragma unroll
                    for (int j = 0; j < 8; ++j) split2(src[i * 8 + j], ph_.h[j], pl_.h[j]);
                    *(uint4*)(vh + doff + i * 8) = ph_.u;
                    *(uint4*)(vl + doff + i * 8) = pl_.u;
                }
            } else if (sector == 1) {         // k: softmax over the 64-px w row
                float mx = -3.0e38f;
                for (int j = 0; j < 64; ++j) mx = fmaxf(mx, src[j]);
                float sum = 0.f;
                for (int j = 0; j < 64; ++j) sum += expf(src[j] - mx);
                float rs = 1.0f / sum;
#pragma unroll
                for (int i = 0; i < 8; ++i) {
                    union { u16 h[8]; uint4 u; } ph_, pl_;
#pragma unroll
                    for (int j = 0; j < 8; ++j) {
                        float p = expf(src[i * 8 + j] - mx) * rs;
                        split2(p, ph_.h[j], pl_.h[j]);
                    }
                    *(uint4*)(kh + doff + i * 8) = ph_.u;
                    *(uint4*)(kl + doff + i * 8) = pl_.u;
                }
            } else {                          // g: sigmoid(x + bg) f32
                float bgv = bg[oloc];
#pragma unroll
                for (int i = 0; i < 16; ++i) {
                    float4 o;
                    float* po = (float*)&o;
#pragma unroll
                    for (int j = 0; j < 4; ++j)
                        po[j] = 1.0f / (1.0f + expf(-(src[i * 4 + j] + bgv)));
                    *(float4*)(gf + doff + i * 4) = o;
                }
            }
        }
        __syncthreads();
    }
}

// ------------------------------------------ q: in-place softmax over h (f32)
__global__ __launch_bounds__(256) void k_smq(float* __restrict__ qf)
{
    __shared__ float img[64 * 65];   // [h][w] padded
    __shared__ float red[256];
    __shared__ float mxv[64];
    __shared__ float smv[64];
    const int t = threadIdx.x;
    float* base = qf + ((size_t)blockIdx.y * 512 + blockIdx.x) * 4096;
#pragma unroll
    for (int i = 0; i < 16; ++i) {
        int n = t + i * 256;
        img[(n >> 6) * 65 + (n & 63)] = base[n];
    }
    __syncthreads();
    const int part = t >> 6, wc = t & 63;
    float mx = -3.0e38f;
    for (int hh = 0; hh < 16; ++hh) mx = fmaxf(mx, img[(part * 16 + hh) * 65 + wc]);
    red[t] = mx;
    __syncthreads();
    if (t < 64) mxv[t] = fmaxf(fmaxf(red[t], red[64 + t]), fmaxf(red[128 + t], red[192 + t]));
    __syncthreads();
    float m = mxv[wc], s = 0.f;
    for (int hh = 0; hh < 16; ++hh) s += expf(img[(part * 16 + hh) * 65 + wc] - m);
    red[t] = s;
    __syncthreads();
    if (t < 64) smv[t] = red[t] + red[64 + t] + red[128 + t] + red[192 + t];
    __syncthreads();
    float rm = mxv[t & 63], rs = 1.0f / smv[t & 63];
#pragma unroll
    for (int i = 0; i < 16; ++i) {
        int n = t + i * 256;
        base[n] = expf(img[(n >> 6) * 65 + (n & 63)] - rm) * rs;
    }
}

// --- per (quarter, bh): kv_part = vsum_local + pk.v^T over 1024 px, ks_part
__global__ __launch_bounds__(512) void k_kv(
    const u16* __restrict__ kh, const u16* __restrict__ kl,
    const u16* __restrict__ vh, const u16* __restrict__ vl,
    float* __restrict__ kvp, float* __restrict__ ksp)
{
    __shared__ float kvl[4096];
    __shared__ float redv[512];
    __shared__ float redk[512];
    __shared__ float vsum[64];
    const int t = threadIdx.x;
    const int qq = blockIdx.x;                 // pixel quarter
    const int bh = blockIdx.y;                 // local bf*8+h
    const int NBH = gridDim.y;
    const size_t hb = (size_t)bh * 64 * 4096;
    const u16* bkh = kh + hb;
    const u16* bkl = kl + hb;
    const u16* bvh = vh + hb;
    const u16* bvl = vl + hb;
#pragma unroll
    for (int i = 0; i < 8; ++i) kvl[t + i * 512] = 0.f;
    __syncthreads();
    const int lane = t & 63, wv = t >> 6;
    f32x4 acc[4][4] = {};
    for (int it = 0; it < 4; ++it) {           // wave covers 128 px, block 1024
        int n = qq * 1024 + wv * 128 + it * 32 + (lane >> 4) * 8;
        bf16x8 ah[4], al[4], bh_[4], bl_[4];
#pragma unroll
        for (int i = 0; i < 4; ++i) {
            size_t ro = (size_t)(i * 16 + (lane & 15)) * 4096 + n;
            ah[i]  = *(const bf16x8*)(bkh + ro);
            al[i]  = *(const bf16x8*)(bkl + ro);
            bh_[i] = *(const bf16x8*)(bvh + ro);
            bl_[i] = *(const bf16x8*)(bvl + ro);
        }
#pragma unroll
        for (int di = 0; di < 4; ++di)
#pragma unroll
            for (int ei = 0; ei < 4; ++ei) {
                acc[di][ei] = __builtin_amdgcn_mfma_f32_16x16x32_bf16(ah[di], bh_[ei], acc[di][ei], 0, 0, 0);
                acc[di][ei] = __builtin_amdgcn_mfma_f32_16x16x32_bf16(ah[di], bl_[ei], acc[di][ei], 0, 0, 0);
                acc[di][ei] = __builtin_amdgcn_mfma_f32_16x16x32_bf16(al[di], bh_[ei], acc[di][ei], 0, 0, 0);
            }
    }
#pragma unroll
    for (int di = 0; di < 4; ++di)
#pragma unroll
        for (int ei = 0; ei < 4; ++ei)
#pragma unroll
            for (int r = 0; r < 4; ++r) {
                int d = di * 16 + (lane >> 4) * 4 + r;
                int e = ei * 16 + (lane & 15);
                atomicAdd(&kvl[d * 64 + e], acc[di][ei][r]);
            }
    // channel sums of v and pk over this block's 1024 px (hi+lo)
    const int e = t & 63, part = t >> 6;
    float sv = 0.f, sk = 0.f;
    const size_t so = (size_t)e * 4096 + qq * 1024 + part * 128;
    for (int i = 0; i < 16; ++i) {
        union { uint4 v; u16 h[8]; } a1, a2, b1, b2;
        a1.v = *(const uint4*)(bvh + so + i * 8);
        a2.v = *(const uint4*)(bvl + so + i * 8);
        b1.v = *(const uint4*)(bkh + so + i * 8);
        b2.v = *(const uint4*)(bkl + so + i * 8);
#pragma unroll
        for (int j = 0; j < 8; ++j) {
            sv += bf2f(a1.h[j]) + bf2f(a2.h[j]);
            sk += bf2f(b1.h[j]) + bf2f(b2.h[j]);
        }
    }
    redv[t] = sv; redk[t] = sk;
    __syncthreads();
    if (t < 64) {
        float a = 0.f, b = 0.f;
#pragma unroll
        for (int p = 0; p < 8; ++p) { a += redv[p * 64 + t]; b += redk[p * 64 + t]; }
        vsum[t] = a;
        ksp[((size_t)qq * NBH + bh) * 64 + t] = 1024.0f + b;  // +1 per pixel (local)
    }
    __syncthreads();
    float* outp = kvp + ((size_t)qq * NBH + bh) * 4096;
#pragma unroll
    for (int i = 0; i < 8; ++i) {
        int idx = t + i * 512;
        outp[idx] = kvl[idx] + vsum[idx & 63];
    }
}

// ----------------- attention: att[n][c'] = (colsum(kv)+pq.kv)*SCALE*z*g, hi/lo
__global__ __launch_bounds__(256) void k_att(
    const float* __restrict__ qf, const float* __restrict__ gf,
    const float* __restrict__ kvp, const float* __restrict__ ksp,
    u16* __restrict__ atth, u16* __restrict__ attl, int NBH)
{
    __shared__ __align__(16) float sh[4352 + 64 + 64 + 16];
    float* kvl = sh;                 // [64][68]
    float* ksl = sh + 4352;
    float* csl = sh + 4416;
    float* kstp = sh + 4480;
    const int t = threadIdx.x;
    const int bh = blockIdx.z * 8 + blockIdx.y;     // local
#pragma unroll
    for (int i = 0; i < 16; ++i) {
        int idx = t + i * 256;
        float s = 0.f;
#pragma unroll
        for (int q = 0; q < 4; ++q) s += kvp[((size_t)q * NBH + bh) * 4096 + idx];
        kvl[(idx >> 6) * 68 + (idx & 63)] = s;
    }
    if (t < 64) {
        float s = 0.f;
#pragma unroll
        for (int q = 0; q < 4; ++q) s += ksp[((size_t)q * NBH + bh) * 64 + t];
        ksl[t] = s;
    }
    __syncthreads();
    if (t < 64) {
        float s = 0.f;
        for (int d = 0; d < 64; ++d) s += kvl[d * 68 + t];
        csl[t] = s;
    }
    if (t == 64) {
        float s = 0.f;
        for (int d = 0; d < 64; ++d) s += ksl[d];
        kstp[0] = s;
    }
    __syncthreads();
    const int n = blockIdx.x * 256 + t;
    const float* qp = qf + ((size_t)bh * 64) * 4096 + n;
    f32x4 sa[16];
#pragma unroll
    for (int i = 0; i < 16; ++i) sa[i] = *(const f32x4*)&csl[i * 4];
    float sz = kstp[0];
    for (int d = 0; d < 64; ++d) {
        float pq = qp[(size_t)d * 4096];
        sz += pq * ksl[d];
        const f32x4* kr = (const f32x4*)&kvl[d * 68];
#pragma unroll
        for (int i = 0; i < 16; ++i) sa[i] += pq * kr[i];
    }
    float zz = 0.125f / fmaxf(sz, 1e-6f);       // SCALE * z
    const float* gp = gf + ((size_t)bh * 64) * 4096 + n;
    const size_t ab = (((size_t)(bh >> 3)) * 4096 + n) * 512 + (bh & 7) * 64;
#pragma unroll
    for (int eo = 0; eo < 8; ++eo) {
        union { u16 h[8]; uint4 u; } ph_, pl_;
#pragma unroll
        for (int j = 0; j < 8; ++j) {
            int e = eo * 8 + j;
            float val = sa[e >> 2][e & 3] * zz * gp[(size_t)e * 4096];
            split2(val, ph_.h[j], pl_.h[j]);
        }
        *(uint4*)(atth + ab + eo * 8) = ph_.u;
        *(uint4*)(attl + ab + eo * 8) = pl_.u;
    }
}

// --------------------------------- out = Wo x att + bo, f32, (b,c,f,h,w) layout
__global__ __launch_bounds__(256) void k_out(
    const u16* __restrict__ Woh, const u16* __restrict__ Wol,
    const u16* __restrict__ atth, const u16* __restrict__ attl,
    const float* __restrict__ bo, float* __restrict__ out, int c0)
{
    __shared__ __align__(16) u16 smem[32768];   // Ah,Al,Bh,Bl [128][64] each
    u16* Ah = smem;
    u16* Al = smem + 8192;
    u16* Bh = smem + 16384;
    u16* Bl = smem + 24576;
    const int t = threadIdx.x;
    const int bfl = blockIdx.z;
    const int bfg = c0 + bfl;
    const int m0 = blockIdx.y * 128;
    const int n0 = blockIdx.x * 128;
    const int lane = t & 63, wv = t >> 6, wm = wv >> 1, wn = wv & 1;
    f32x4 acc[4][4] = {};
    const u16* Aph = Woh + (size_t)m0 * 512;
    const u16* Apl = Wol + (size_t)m0 * 512;
    const u16* Bph = atth + ((size_t)bfl * 4096 + n0) * 512;
    const u16* Bpl = attl + ((size_t)bfl * 4096 + n0) * 512;
    const int srow = t >> 3, sci = t & 7;
    for (int kt = 0; kt < 8; ++kt) {
        const int k0 = kt * 64;
#pragma unroll
        for (int p = 0; p < 4; ++p) {
            int row = srow + p * 32;
            size_t go = (size_t)row * 512 + k0 + sci * 8;
            int sc = (sci ^ (row & 7)) * 8;
            *(uint4*)(Ah + row * 64 + sc) = *(const uint4*)(Aph + go);
            *(uint4*)(Al + row * 64 + sc) = *(const uint4*)(Apl + go);
            *(uint4*)(Bh + row * 64 + sc) = *(const uint4*)(Bph + go);
            *(uint4*)(Bl + row * 64 + sc) = *(const uint4*)(Bpl + go);
        }
        __syncthreads();
#pragma unroll
        for (int kk = 0; kk < 2; ++kk) {
            bf16x8 afh[4], afl[4], bfh[4], bfl_[4];
#pragma unroll
            for (int i = 0; i < 4; ++i) {
                int ra = wm * 64 + i * 16 + (lane & 15);
                int ca = ((kk * 4 + (lane >> 4)) ^ (ra & 7)) * 8;
                afh[i] = *(const bf16x8*)(Ah + ra * 64 + ca);
                afl[i] = *(const bf16x8*)(Al + ra * 64 + ca);
                int rb = wn * 64 + i * 16 + (lane & 15);
                int cb = ((kk * 4 + (lane >> 4)) ^ (rb & 7)) * 8;
                bfh[i] = *(const bf16x8*)(Bh + rb * 64 + cb);
                bfl_[i] = *(const bf16x8*)(Bl + rb * 64 + cb);
            }
#pragma unroll
            for (int mi = 0; mi < 4; ++mi)
#pragma unroll
                for (int ni = 0; ni < 4; ++ni) {
                    acc[mi][ni] = __builtin_amdgcn_mfma_f32_16x16x32_bf16(afh[mi], bfh[ni], acc[mi][ni], 0, 0, 0);
                    acc[mi][ni] = __builtin_amdgcn_mfma_f32_16x16x32_bf16(afh[mi], bfl_[ni], acc[mi][ni], 0, 0, 0);
                    acc[mi][ni] = __builtin_amdgcn_mfma_f32_16x16x32_bf16(afl[mi], bfh[ni], acc[mi][ni], 0, 0, 0);
                }
        }
        __syncthreads();
    }
    const int b_ = bfg >> 4, f_ = bfg & 15;
#pragma unroll
    for (int mi = 0; mi < 4; ++mi)
#pragma unroll
        for (int ni = 0; ni < 4; ++ni)
#pragma unroll
            for (int r = 0; r < 4; ++r) {
                int o = m0 + wm * 64 + mi * 16 + (lane >> 4) * 4 + r;
                int nn = n0 + wn * 64 + ni * 16 + (lane & 15);
                out[(((size_t)b_ * 256 + o) * 16 + f_) * 4096 + nn] = acc[mi][ni][r] + bo[o];
            }
}

extern "C" void kernel_launch(void* const* d_in, const int* in_sizes, int n_in,
                              void* d_out, int out_size, void* d_ws, size_t ws_size,
                              hipStream_t stream)
{
    const float* x  = (const float*)d_in[0];
    const float* Wq = (const float*)d_in[1];
    const float* Wk = (const float*)d_in[2];
    const float* Wv = (const float*)d_in[3];
    const float* Wg = (const float*)d_in[4];
    const float* bg = (const float*)d_in[5];
    const float* Wo = (const float*)d_in[6];
    const float* bo = (const float*)d_in[7];
    float* out = (float*)d_out;
    char* ws = (char*)d_ws;

    // Per-bf bytes: xh/xl 2*2,097,152 | k+q region 8,388,608 | v+g region 8,388,608
    //               atth/attl 2*4,194,304 | kvp 524,288 | ksp 8,192  = 29,892,608
    // Fixed: Wh/Wl 2*1,048,576 + Woh/Wol 2*262,144 = 2,621,440
    const size_t PER_BF = 29892608ull;
    const size_t FIXED  = 2621440ull;
    int CH = 32;
    while (CH > 1 && FIXED + (size_t)CH * PER_BF > ws_size) CH >>= 1;
    const int nch = 32 / CH;

    u16* Wh  = (u16*)(ws);
    u16* Wl  = (u16*)(ws + 1048576);
    u16* Woh = (u16*)(ws + 2097152);
    u16* Wol = (u16*)(ws + 2359296);
    char* dyn = ws + FIXED;
    u16*   xh   = (u16*)(dyn);
    u16*   xl   = (u16*)(dyn + (size_t)CH * 2097152);
    u16*   kh   = (u16*)(dyn + (size_t)CH * 4194304);   // pass1: qf f32 overwrites kh+kl
    u16*   kl   = (u16*)(dyn + (size_t)CH * 8388608);
    u16*   vh   = (u16*)(dyn + (size_t)CH * 12582912);  // pass1: gf f32 overwrites vh+vl
    u16*   vl   = (u16*)(dyn + (size_t)CH * 16777216);
    u16*   atth = (u16*)(dyn + (size_t)CH * 20971520);
    u16*   attl = (u16*)(dyn + (size_t)CH * 25165824);
    float* kvp  = (float*)(dyn + (size_t)CH * 29360128);
    float* ksp  = (float*)(dyn + (size_t)CH * 29884416);
    float* qf   = (float*)kh;
    float* gf   = (float*)vh;

    k_cvt_w<<<dim3(2560), dim3(256), 0, stream>>>(Wq, Wk, Wv, Wg, Wo, Wh, Wl, Woh, Wol);

    for (int c = 0; c < nch; ++c) {
        const int c0 = c * CH;
        k_cvt_x<<<dim3(32, CH),    dim3(256), 0, stream>>>(x, xh, xl, c0);
        k_proj <<<dim3(32, 8, CH), dim3(256), 0, stream>>>(Wh, Wl, xh, xl, bg,
                                                           kh, kl, vh, vl, qf, gf, 0); // k,v
        k_kv   <<<dim3(4, CH * 8), dim3(512), 0, stream>>>(kh, kl, vh, vl, kvp, ksp);
        k_proj <<<dim3(32, 8, CH), dim3(256), 0, stream>>>(Wh, Wl, xh, xl, bg,
                                                           kh, kl, vh, vl, qf, gf, 1); // q,g
        k_smq  <<<dim3(512, CH),   dim3(256), 0, stream>>>(qf);
        k_att  <<<dim3(16, 8, CH), dim3(256), 0, stream>>>(qf, gf, kvp, ksp, atth, attl, CH * 8);
        k_out  <<<dim3(32, 2, CH), dim3(256), 0, stream>>>(Woh, Wol, atth, attl, bo, out, c0);
    }
}

// Round 4
// 1898.498 us; speedup vs baseline: 1.0759x; 1.0759x over previous
//
#include <hip/hip_runtime.h>

// GatedSpatialLinearAttention on MI355X (gfx950). Round 4.
// Split-bf16 (hi+lo) 3-pass MFMA emulation of fp32 GEMMs (passed R3, absmax 2^-18).
// R4: k_kv rewritten (LDS-staged, single-pass, ones-row sums); global_load_lds
// staging (pre-swizzled source, linear LDS dest) in k_proj/k_out/k_kv.

typedef unsigned short u16;
typedef unsigned int u32;
typedef __bf16 bf16x8 __attribute__((ext_vector_type(8)));
typedef float f32x4 __attribute__((ext_vector_type(4)));

typedef const __attribute__((address_space(1))) void* gas_t;
typedef __attribute__((address_space(3))) void* las_t;
__device__ __forceinline__ void gll16(const void* g, void* l) {
    __builtin_amdgcn_global_load_lds((gas_t)g, (las_t)l, 16, 0, 0);
}

__device__ inline float bf2f(u16 v) { union { u32 i; float f; } u; u.i = ((u32)v) << 16; return u.f; }
__device__ inline u16 f2bf(float f) {
    union { float f; u32 i; } u; u.f = f;
    u32 r = (u.i + 0x7fffu + ((u.i >> 16) & 1u)) >> 16;   // RNE
    return (u16)r;
}
__device__ inline void split2(float v, u16& h, u16& l) {
    h = f2bf(v);
    l = f2bf(v - bf2f(h));
}

// ------------------------------------------------- cvt weights to hi/lo pairs
__global__ void k_cvt_w(const float* __restrict__ Wq, const float* __restrict__ Wk,
                        const float* __restrict__ Wv, const float* __restrict__ Wg,
                        const float* __restrict__ Wo,
                        u16* __restrict__ Wh, u16* __restrict__ Wl,
                        u16* __restrict__ Woh, u16* __restrict__ Wol)
{
    int idx = blockIdx.x * 256 + threadIdx.x;
    if (idx < 524288) {                       // W_all[2048][256] = [q;k;v;g]
        int o = idx >> 8, c = idx & 255;
        int which = o >> 9, r = o & 511;
        const float* s = (which == 0) ? Wq : (which == 1) ? Wk : (which == 2) ? Wv : Wg;
        u16 h, l; split2(s[r * 256 + c], h, l);
        Wh[idx] = h; Wl[idx] = l;
    } else {
        int j = idx - 524288;                 // Wo[256][512]
        if (j < 131072) { u16 h, l; split2(Wo[j], h, l); Woh[j] = h; Wol[j] = l; }
    }
}

// ----------------------- cvt x -> xh/xl [bf_local][n][c] bf16 pairs (chunked)
__global__ __launch_bounds__(256) void k_cvt_x(const float* __restrict__ x,
                                               u16* __restrict__ xh, u16* __restrict__ xl,
                                               int c0)
{
    __shared__ __align__(16) u16 tileh[64 * 132];   // [n_local][c_local], pad 132
    __shared__ __align__(16) u16 tilel[64 * 132];
    const int t = threadIdx.x;
    const int bfl = blockIdx.y;
    const int bfg = c0 + bfl;
    const int n0 = blockIdx.x * 128;
    const int b_ = bfg >> 4, f_ = bfg & 15;
    for (int s = 0; s < 2; ++s) {                   // n-half (64 px)
        for (int ch2 = 0; ch2 < 2; ++ch2) {         // c-half (128 ch)
            __syncthreads();
            for (int p = 0; p < 8; ++p) {
                int cl = p * 16 + (t >> 4);
                int c = ch2 * 128 + cl;
                const float* sp = x + (((size_t)b_ * 256 + c) * 16 + f_) * 4096
                                    + n0 + s * 64 + (t & 15) * 4;
                float4 v = *(const float4*)sp;
                float vv[4] = { v.x, v.y, v.z, v.w };
#pragma unroll
                for (int j = 0; j < 4; ++j) {
                    int nl = (t & 15) * 4 + j;
                    u16 h, l; split2(vv[j], h, l);
                    tileh[nl * 132 + cl] = h;
                    tilel[nl * 132 + cl] = l;
                }
            }
            __syncthreads();
#pragma unroll
            for (int i = 0; i < 4; ++i) {
                int flat = t + i * 256;             // 64n x 16 groups-of-8c
                int nn = flat >> 4, cc = flat & 15;
                size_t off = ((size_t)bfl * 4096 + n0 + s * 64 + nn) * 256 + ch2 * 128 + cc * 8;
                *(uint4*)(xh + off) = *(const uint4*)(tileh + nn * 132 + cc * 8);
                *(uint4*)(xl + off) = *(const uint4*)(tilel + nn * 132 + cc * 8);
            }
        }
    }
}

// ------------------------------------------------------- fused projection pass
// pass 0: k(512..1023)->kh/kl softmax-w, v(1024..1535)->vh/vl raw
// pass 1: q(0..511)->qf f32 raw, g(1536..2047)->gf f32 sigmoid(+bg)
__global__ __launch_bounds__(256) void k_proj(
    const u16* __restrict__ Wh, const u16* __restrict__ Wl,
    const u16* __restrict__ xh, const u16* __restrict__ xl,
    const float* __restrict__ bg,
    u16* __restrict__ kh, u16* __restrict__ kl,
    u16* __restrict__ vh, u16* __restrict__ vl,
    float* __restrict__ qf, float* __restrict__ gf, int pass)
{
    __shared__ __align__(16) char smem[65536];
    u16* Ah = (u16*)smem;                 // [128][64] each; LDS linear,
    u16* Al = (u16*)(smem + 16384);       // source pre-swizzled (XOR chunk^row&7)
    u16* Bh = (u16*)(smem + 32768);
    u16* Bl = (u16*)(smem + 49152);
    float* Csh = (float*)smem;            // [128][69] f32, reused after K loop
    const int t = threadIdx.x;
    const int bfl = blockIdx.z;
    const int by = blockIdx.y;
    const int m0 = (pass == 0) ? (512 + by * 128)
                               : ((by < 4) ? by * 128 : 1536 + (by - 4) * 128);
    const int n0 = blockIdx.x * 128;
    const int lane = t & 63, wv = t >> 6, wm = wv >> 1, wn = wv & 1;
    f32x4 acc[4][4] = {};
    const u16* Aph = Wh + (size_t)m0 * 256;
    const u16* Apl = Wl + (size_t)m0 * 256;
    const u16* Bph = xh + ((size_t)bfl * 4096 + n0) * 256;
    const u16* Bpl = xl + ((size_t)bfl * 4096 + n0) * 256;

    for (int kt = 0; kt < 4; ++kt) {
        const int k0 = kt * 64;
        // stage 4x [128][64] via global_load_lds; seg = 1KB = 8 rows of 128B
#pragma unroll
        for (int jj = 0; jj < 4; ++jj) {
            int s = wv * 4 + jj;
            int row = s * 8 + (lane >> 3);
            int csrc = (lane & 7) ^ (row & 7);
            size_t go = (size_t)row * 256 + k0 + csrc * 8;
            gll16(Aph + go, Ah + s * 512);
            gll16(Apl + go, Al + s * 512);
            gll16(Bph + go, Bh + s * 512);
            gll16(Bpl + go, Bl + s * 512);
        }
        __syncthreads();
#pragma unroll
        for (int kk = 0; kk < 2; ++kk) {
            bf16x8 afh[4], afl[4], bfh[4], bfl_[4];
#pragma unroll
            for (int i = 0; i < 4; ++i) {
                int ra = wm * 64 + i * 16 + (lane & 15);
                int ca = ((kk * 4 + (lane >> 4)) ^ (ra & 7)) * 8;
                afh[i] = *(const bf16x8*)(Ah + ra * 64 + ca);
                afl[i] = *(const bf16x8*)(Al + ra * 64 + ca);
                int rb = wn * 64 + i * 16 + (lane & 15);
                int cb = ((kk * 4 + (lane >> 4)) ^ (rb & 7)) * 8;
                bfh[i] = *(const bf16x8*)(Bh + rb * 64 + cb);
                bfl_[i] = *(const bf16x8*)(Bl + rb * 64 + cb);
            }
#pragma unroll
            for (int mi = 0; mi < 4; ++mi)
#pragma unroll
                for (int ni = 0; ni < 4; ++ni) {
                    acc[mi][ni] = __builtin_amdgcn_mfma_f32_16x16x32_bf16(afh[mi], bfh[ni], acc[mi][ni], 0, 0, 0);
                    acc[mi][ni] = __builtin_amdgcn_mfma_f32_16x16x32_bf16(afh[mi], bfl_[ni], acc[mi][ni], 0, 0, 0);
                    acc[mi][ni] = __builtin_amdgcn_mfma_f32_16x16x32_bf16(afl[mi], bfh[ni], acc[mi][ni], 0, 0, 0);
                }
        }
        __syncthreads();
    }

    const int sector = m0 >> 9;               // 0:q 1:k 2:v 3:g
    for (int ph = 0; ph < 2; ++ph) {
        if (wn == ph) {
#pragma unroll
            for (int mi = 0; mi < 4; ++mi)
#pragma unroll
                for (int ni = 0; ni < 4; ++ni)
#pragma unroll
                    for (int r = 0; r < 4; ++r) {
                        int gr = wm * 64 + mi * 16 + (lane >> 4) * 4 + r;
                        int gcl = ni * 16 + (lane & 15);
                        Csh[gr * 69 + gcl] = acc[mi][ni][r];
                    }
        }
        __syncthreads();
        if (t < 128) {
            const float* src = Csh + t * 69;
            const int oloc = (m0 & 511) + t;
            const size_t doff = ((size_t)bfl * 512 + oloc) * 4096 + n0 + ph * 64;
            if (sector == 0) {                // q raw f32
#pragma unroll
                for (int i = 0; i < 16; ++i) {
                    float4 o = { src[i * 4], src[i * 4 + 1], src[i * 4 + 2], src[i * 4 + 3] };
                    *(float4*)(qf + doff + i * 4) = o;
                }
            } else if (sector == 2) {         // v split pair
#pragma unroll
                for (int i = 0; i < 8; ++i) {
                    union { u16 h[8]; uint4 u; } ph_, pl_;
#pragma unroll
                    for (int j = 0; j < 8; ++j) split2(src[i * 8 + j], ph_.h[j], pl_.h[j]);
                    *(uint4*)(vh + doff + i * 8) = ph_.u;
                    *(uint4*)(vl + doff + i * 8) = pl_.u;
                }
            } else if (sector == 1) {         // k: softmax over the 64-px w row
                float mx = -3.0e38f;
                for (int j = 0; j < 64; ++j) mx = fmaxf(mx, src[j]);
                float sum = 0.f;
                for (int j = 0; j < 64; ++j) sum += expf(src[j] - mx);
                float rs = 1.0f / sum;
#pragma unroll
                for (int i = 0; i < 8; ++i) {
                    union { u16 h[8]; uint4 u; } ph_, pl_;
#pragma unroll
                    for (int j = 0; j < 8; ++j) {
                        float p = expf(src[i * 8 + j] - mx) * rs;
                        split2(p, ph_.h[j], pl_.h[j]);
                    }
                    *(uint4*)(kh + doff + i * 8) = ph_.u;
                    *(uint4*)(kl + doff + i * 8) = pl_.u;
                }
            } else {                          // g: sigmoid(x + bg) f32
                float bgv = bg[oloc];
#pragma unroll
                for (int i = 0; i < 16; ++i) {
                    float4 o;
                    float* po = (float*)&o;
#pragma unroll
                    for (int j = 0; j < 4; ++j)
                        po[j] = 1.0f / (1.0f + expf(-(src[i * 4 + j] + bgv)));
                    *(float4*)(gf + doff + i * 4) = o;
                }
            }
        }
        __syncthreads();
    }
}

// ------------------------------------------ q: in-place softmax over h (f32)
__global__ __launch_bounds__(256) void k_smq(float* __restrict__ qf)
{
    __shared__ float img[64 * 65];   // [h][w] padded
    __shared__ float red[256];
    __shared__ float mxv[64];
    __shared__ float smv[64];
    const int t = threadIdx.x;
    float* base = qf + ((size_t)blockIdx.y * 512 + blockIdx.x) * 4096;
#pragma unroll
    for (int i = 0; i < 16; ++i) {
        int n = t + i * 256;
        img[(n >> 6) * 65 + (n & 63)] = base[n];
    }
    __syncthreads();
    const int part = t >> 6, wc = t & 63;
    float mx = -3.0e38f;
    for (int hh = 0; hh < 16; ++hh) mx = fmaxf(mx, img[(part * 16 + hh) * 65 + wc]);
    red[t] = mx;
    __syncthreads();
    if (t < 64) mxv[t] = fmaxf(fmaxf(red[t], red[64 + t]), fmaxf(red[128 + t], red[192 + t]));
    __syncthreads();
    float m = mxv[wc], s = 0.f;
    for (int hh = 0; hh < 16; ++hh) s += expf(img[(part * 16 + hh) * 65 + wc] - m);
    red[t] = s;
    __syncthreads();
    if (t < 64) smv[t] = red[t] + red[64 + t] + red[128 + t] + red[192 + t];
    __syncthreads();
    float rm = mxv[t & 63], rs = 1.0f / smv[t & 63];
#pragma unroll
    for (int i = 0; i < 16; ++i) {
        int n = t + i * 256;
        base[n] = expf(img[(n >> 6) * 65 + (n & 63)] - rm) * rs;
    }
}

// ---- per (octant, bh): kv,vsum,ksum partials over 512 px in ONE LDS-staged pass.
// Ones-row trick: A-row64=1 => row64 of acc = vsum; B-col64=1 => col64 = ksum.
__global__ __launch_bounds__(256) void k_kv(
    const u16* __restrict__ kh, const u16* __restrict__ kl,
    const u16* __restrict__ vh, const u16* __restrict__ vl,
    float* __restrict__ kvp, float* __restrict__ vsp, float* __restrict__ ksp)
{
    __shared__ __align__(16) char smem[65536];
    u16* Kh = (u16*)smem;                 // [64][128] each; linear LDS,
    u16* Kl = (u16*)(smem + 16384);       // pre-swizzled source (chunk^row&7)
    u16* Vh = (u16*)(smem + 32768);
    u16* Vl = (u16*)(smem + 49152);
    float* mrg = (float*)smem;            // reuse: [64][68] kv + vs[64] + ks[64]
    const int t = threadIdx.x;
    const int oct = blockIdx.x;           // 0..7 pixel octant (512 px)
    const int bh = blockIdx.y;            // local bf*8+h
    const int NBH = gridDim.y;
    const int lane = t & 63, wv = t >> 6;
    const size_t hb = (size_t)bh * 64 * 4096;

    f32x4 acc[5][5] = {};
    bf16x8 ones;
#pragma unroll
    for (int j = 0; j < 8; ++j) ones[j] = (lane & 15) == 0 ? (__bf16)1.0f : (__bf16)0.0f;

    for (int cc = 0; cc < 4; ++cc) {      // 4 chunks of 128 px
        const int pxc = oct * 512 + cc * 128;
#pragma unroll
        for (int jj = 0; jj < 4; ++jj) {  // stage: seg = 1KB = 4 rows of 256B
            int s = wv * 4 + jj;
            int row = s * 4 + (lane >> 4);
            int csrc = (lane & 15) ^ (row & 7);
            size_t go = hb + (size_t)row * 4096 + pxc + csrc * 8;
            gll16(kh + go, Kh + s * 512);
            gll16(kl + go, Kl + s * 512);
            gll16(vh + go, Vh + s * 512);
            gll16(vl + go, Vl + s * 512);
        }
        __syncthreads();
        bf16x8 ah[4], al[4], bh_[4], bl_[4];
#pragma unroll
        for (int i = 0; i < 4; ++i) {     // wave's K-slice: px wv*32..+32
            int ra = i * 16 + (lane & 15);
            int kc = (wv * 4 + (lane >> 4)) ^ (ra & 7);
            int off = ra * 128 + kc * 8;
            ah[i]  = *(const bf16x8*)(Kh + off);
            al[i]  = *(const bf16x8*)(Kl + off);
            bh_[i] = *(const bf16x8*)(Vh + off);
            bl_[i] = *(const bf16x8*)(Vl + off);
        }
        // pass1 h*h (5x5), pass2 h*l (5x4), pass3 l*h (4x5)
#pragma unroll
        for (int di = 0; di < 5; ++di) {
            bf16x8 a = (di < 4) ? ah[di] : ones;
#pragma unroll
            for (int ei = 0; ei < 5; ++ei) {
                bf16x8 b = (ei < 4) ? bh_[ei] : ones;
                acc[di][ei] = __builtin_amdgcn_mfma_f32_16x16x32_bf16(a, b, acc[di][ei], 0, 0, 0);
            }
        }
#pragma unroll
        for (int di = 0; di < 5; ++di) {
            bf16x8 a = (di < 4) ? ah[di] : ones;
#pragma unroll
            for (int ei = 0; ei < 4; ++ei)
                acc[di][ei] = __builtin_amdgcn_mfma_f32_16x16x32_bf16(a, bl_[ei], acc[di][ei], 0, 0, 0);
        }
#pragma unroll
        for (int di = 0; di < 4; ++di)
#pragma unroll
            for (int ei = 0; ei < 5; ++ei) {
                bf16x8 b = (ei < 4) ? bh_[ei] : ones;
                acc[di][ei] = __builtin_amdgcn_mfma_f32_16x16x32_bf16(al[di], b, acc[di][ei], 0, 0, 0);
            }
        __syncthreads();
    }

    // merge 4 waves via LDS (reuse smem)
    float* kvm = mrg;                 // [64][68]
    float* vsm = mrg + 64 * 68;
    float* ksm = mrg + 64 * 68 + 64;
    for (int i = t; i < 64 * 68 + 128; i += 256) mrg[i] = 0.f;
    __syncthreads();
#pragma unroll
    for (int di = 0; di < 4; ++di)
#pragma unroll
        for (int ei = 0; ei < 4; ++ei)
#pragma unroll
            for (int r = 0; r < 4; ++r) {
                int d = di * 16 + (lane >> 4) * 4 + r;
                int e = ei * 16 + (lane & 15);
                atomicAdd(&kvm[d * 68 + e], acc[di][ei][r]);
            }
    if (lane < 16) {
#pragma unroll
        for (int ei = 0; ei < 4; ++ei) atomicAdd(&vsm[ei * 16 + lane], acc[4][ei][0]);
    }
    if ((lane & 15) == 0) {
#pragma unroll
        for (int di = 0; di < 4; ++di)
#pragma unroll
            for (int r = 0; r < 4; ++r)
                atomicAdd(&ksm[di * 16 + (lane >> 4) * 4 + r], acc[di][4][r]);
    }
    __syncthreads();
    float* op = kvp + ((size_t)oct * NBH + bh) * 4096;
#pragma unroll
    for (int i = 0; i < 16; ++i) {
        int idx = t + i * 256;
        op[idx] = kvm[(idx >> 6) * 68 + (idx & 63)];
    }
    if (t < 64) {
        vsp[((size_t)oct * NBH + bh) * 64 + t] = vsm[t];
        ksp[((size_t)oct * NBH + bh) * 64 + t] = 512.0f + ksm[t];  // +1 per px
    }
}

// ----------------- attention: att[n][c'] = (colsum(kv)+pq.kv)*SCALE*z*g, hi/lo
__global__ __launch_bounds__(256) void k_att(
    const float* __restrict__ qf, const float* __restrict__ gf,
    const float* __restrict__ kvp, const float* __restrict__ vsp,
    const float* __restrict__ ksp,
    u16* __restrict__ atth, u16* __restrict__ attl, int NBH)
{
    __shared__ __align__(16) float sh[4352 + 64 + 64 + 64 + 16];
    float* kvl = sh;                 // [64][68]
    float* vsl = sh + 4352;
    float* ksl = sh + 4416;
    float* csl = sh + 4480;
    float* kstp = sh + 4544;
    const int t = threadIdx.x;
    const int bh = blockIdx.z * 8 + blockIdx.y;     // local
    if (t < 64) {
        float a = 0.f, b = 0.f;
#pragma unroll
        for (int o = 0; o < 8; ++o) {
            a += vsp[((size_t)o * NBH + bh) * 64 + t];
            b += ksp[((size_t)o * NBH + bh) * 64 + t];
        }
        vsl[t] = a; ksl[t] = b;
    }
    __syncthreads();
#pragma unroll
    for (int i = 0; i < 16; ++i) {
        int idx = t + i * 256;
        float s = vsl[idx & 63];
#pragma unroll
        for (int o = 0; o < 8; ++o) s += kvp[((size_t)o * NBH + bh) * 4096 + idx];
        kvl[(idx >> 6) * 68 + (idx & 63)] = s;
    }
    __syncthreads();
    if (t < 64) {
        float s = 0.f;
        for (int d = 0; d < 64; ++d) s += kvl[d * 68 + t];
        csl[t] = s;
    }
    if (t == 64) {
        float s = 0.f;
        for (int d = 0; d < 64; ++d) s += ksl[d];
        kstp[0] = s;
    }
    __syncthreads();
    const int n = blockIdx.x * 256 + t;
    const float* qp = qf + ((size_t)bh * 64) * 4096 + n;
    f32x4 sa[16];
#pragma unroll
    for (int i = 0; i < 16; ++i) sa[i] = *(const f32x4*)&csl[i * 4];
    float sz = kstp[0];
    for (int d = 0; d < 64; ++d) {
        float pq = qp[(size_t)d * 4096];
        sz += pq * ksl[d];
        const f32x4* kr = (const f32x4*)&kvl[d * 68];
#pragma unroll
        for (int i = 0; i < 16; ++i) sa[i] += pq * kr[i];
    }
    float zz = 0.125f / fmaxf(sz, 1e-6f);       // SCALE * z
    const float* gp = gf + ((size_t)bh * 64) * 4096 + n;
    const size_t ab = (((size_t)(bh >> 3)) * 4096 + n) * 512 + (bh & 7) * 64;
#pragma unroll
    for (int eo = 0; eo < 8; ++eo) {
        union { u16 h[8]; uint4 u; } ph_, pl_;
#pragma unroll
        for (int j = 0; j < 8; ++j) {
            int e = eo * 8 + j;
            float val = sa[e >> 2][e & 3] * zz * gp[(size_t)e * 4096];
            split2(val, ph_.h[j], pl_.h[j]);
        }
        *(uint4*)(atth + ab + eo * 8) = ph_.u;
        *(uint4*)(attl + ab + eo * 8) = pl_.u;
    }
}

// --------------------------------- out = Wo x att + bo, f32, (b,c,f,h,w) layout
__global__ __launch_bounds__(256) void k_out(
    const u16* __restrict__ Woh, const u16* __restrict__ Wol,
    const u16* __restrict__ atth, const u16* __restrict__ attl,
    const float* __restrict__ bo, float* __restrict__ out, int c0)
{
    __shared__ __align__(16) u16 smem[32768];   // Ah,Al,Bh,Bl [128][64] each
    u16* Ah = smem;
    u16* Al = smem + 8192;
    u16* Bh = smem + 16384;
    u16* Bl = smem + 24576;
    const int t = threadIdx.x;
    const int bfl = blockIdx.z;
    const int bfg = c0 + bfl;
    const int m0 = blockIdx.y * 128;
    const int n0 = blockIdx.x * 128;
    const int lane = t & 63, wv = t >> 6, wm = wv >> 1, wn = wv & 1;
    f32x4 acc[4][4] = {};
    const u16* Aph = Woh + (size_t)m0 * 512;
    const u16* Apl = Wol + (size_t)m0 * 512;
    const u16* Bph = atth + ((size_t)bfl * 4096 + n0) * 512;
    const u16* Bpl = attl + ((size_t)bfl * 4096 + n0) * 512;
    for (int kt = 0; kt < 8; ++kt) {
        const int k0 = kt * 64;
#pragma unroll
        for (int jj = 0; jj < 4; ++jj) {
            int s = wv * 4 + jj;
            int row = s * 8 + (lane >> 3);
            int csrc = (lane & 7) ^ (row & 7);
            size_t go = (size_t)row * 512 + k0 + csrc * 8;
            gll16(Aph + go, Ah + s * 512);
            gll16(Apl + go, Al + s * 512);
            gll16(Bph + go, Bh + s * 512);
            gll16(Bpl + go, Bl + s * 512);
        }
        __syncthreads();
#pragma unroll
        for (int kk = 0; kk < 2; ++kk) {
            bf16x8 afh[4], afl[4], bfh[4], bfl_[4];
#pragma unroll
            for (int i = 0; i < 4; ++i) {
                int ra = wm * 64 + i * 16 + (lane & 15);
                int ca = ((kk * 4 + (lane >> 4)) ^ (ra & 7)) * 8;
                afh[i] = *(const bf16x8*)(Ah + ra * 64 + ca);
                afl[i] = *(const bf16x8*)(Al + ra * 64 + ca);
                int rb = wn * 64 + i * 16 + (lane & 15);
                int cb = ((kk * 4 + (lane >> 4)) ^ (rb & 7)) * 8;
                bfh[i] = *(const bf16x8*)(Bh + rb * 64 + cb);
                bfl_[i] = *(const bf16x8*)(Bl + rb * 64 + cb);
            }
#pragma unroll
            for (int mi = 0; mi < 4; ++mi)
#pragma unroll
                for (int ni = 0; ni < 4; ++ni) {
                    acc[mi][ni] = __builtin_amdgcn_mfma_f32_16x16x32_bf16(afh[mi], bfh[ni], acc[mi][ni], 0, 0, 0);
                    acc[mi][ni] = __builtin_amdgcn_mfma_f32_16x16x32_bf16(afh[mi], bfl_[ni], acc[mi][ni], 0, 0, 0);
                    acc[mi][ni] = __builtin_amdgcn_mfma_f32_16x16x32_bf16(afl[mi], bfh[ni], acc[mi][ni], 0, 0, 0);
                }
        }
        __syncthreads();
    }
    const int b_ = bfg >> 4, f_ = bfg & 15;
#pragma unroll
    for (int mi = 0; mi < 4; ++mi)
#pragma unroll
        for (int ni = 0; ni < 4; ++ni)
#pragma unroll
            for (int r = 0; r < 4; ++r) {
                int o = m0 + wm * 64 + mi * 16 + (lane >> 4) * 4 + r;
                int nn = n0 + wn * 64 + ni * 16 + (lane & 15);
                out[(((size_t)b_ * 256 + o) * 16 + f_) * 4096 + nn] = acc[mi][ni][r] + bo[o];
            }
}

extern "C" void kernel_launch(void* const* d_in, const int* in_sizes, int n_in,
                              void* d_out, int out_size, void* d_ws, size_t ws_size,
                              hipStream_t stream)
{
    const float* x  = (const float*)d_in[0];
    const float* Wq = (const float*)d_in[1];
    const float* Wk = (const float*)d_in[2];
    const float* Wv = (const float*)d_in[3];
    const float* Wg = (const float*)d_in[4];
    const float* bg = (const float*)d_in[5];
    const float* Wo = (const float*)d_in[6];
    const float* bo = (const float*)d_in[7];
    float* out = (float*)d_out;
    char* ws = (char*)d_ws;

    // Per-bf bytes: xh/xl 2*2,097,152 | kh/kl/vh/vl 4*4,194,304 | atth/attl 2*4,194,304
    //               kvp 1,048,576 | vsp 16,384 | ksp 16,384  = 30,441,472
    const size_t PER_BF = 30441472ull;
    const size_t FIXED  = 2621440ull;
    int CH = 32;
    while (CH > 1 && FIXED + (size_t)CH * PER_BF > ws_size) CH >>= 1;
    const int nch = 32 / CH;

    u16* Wh  = (u16*)(ws);
    u16* Wl  = (u16*)(ws + 1048576);
    u16* Woh = (u16*)(ws + 2097152);
    u16* Wol = (u16*)(ws + 2359296);
    char* dyn = ws + FIXED;
    u16*   xh   = (u16*)(dyn);
    u16*   xl   = (u16*)(dyn + (size_t)CH * 2097152);
    u16*   kh   = (u16*)(dyn + (size_t)CH * 4194304);   // pass1: qf f32 overwrites kh+kl
    u16*   kl   = (u16*)(dyn + (size_t)CH * 8388608);
    u16*   vh   = (u16*)(dyn + (size_t)CH * 12582912);  // pass1: gf f32 overwrites vh+vl
    u16*   vl   = (u16*)(dyn + (size_t)CH * 16777216);
    u16*   atth = (u16*)(dyn + (size_t)CH * 20971520);
    u16*   attl = (u16*)(dyn + (size_t)CH * 25165824);
    float* kvp  = (float*)(dyn + (size_t)CH * 29360128);
    float* vsp  = (float*)(dyn + (size_t)CH * 30408704);
    float* ksp  = (float*)(dyn + (size_t)CH * 30425088);
    float* qf   = (float*)kh;
    float* gf   = (float*)vh;

    k_cvt_w<<<dim3(2560), dim3(256), 0, stream>>>(Wq, Wk, Wv, Wg, Wo, Wh, Wl, Woh, Wol);

    for (int c = 0; c < nch; ++c) {
        const int c0 = c * CH;
        k_cvt_x<<<dim3(32, CH),    dim3(256), 0, stream>>>(x, xh, xl, c0);
        k_proj <<<dim3(32, 8, CH), dim3(256), 0, stream>>>(Wh, Wl, xh, xl, bg,
                                                           kh, kl, vh, vl, qf, gf, 0); // k,v
        k_kv   <<<dim3(8, CH * 8), dim3(256), 0, stream>>>(kh, kl, vh, vl, kvp, vsp, ksp);
        k_proj <<<dim3(32, 8, CH), dim3(256), 0, stream>>>(Wh, Wl, xh, xl, bg,
                                                           kh, kl, vh, vl, qf, gf, 1); // q,g
        k_smq  <<<dim3(512, CH),   dim3(256), 0, stream>>>(qf);
        k_att  <<<dim3(16, 8, CH), dim3(256), 0, stream>>>(qf, gf, kvp, vsp, ksp, atth, attl, CH * 8);
        k_out  <<<dim3(32, 2, CH), dim3(256), 0, stream>>>(Woh, Wol, atth, attl, bo, out, c0);
    }
}

// Round 6
// 1750.891 us; speedup vs baseline: 1.1666x; 1.0843x over previous
//
#include <hip/hip_runtime.h>

// GatedSpatialLinearAttention on MI355X (gfx950). Round 5 (resubmit; R5 never ran).
// Split-bf16 (hi+lo) 3-pass MFMA emulation of fp32 GEMMs throughout.
// R5: k_att MFMA-ized (kvT direct-global A-frags + swizzled LDS q B-frags);
// k_proj single dispatch w/ pixel-major q; k_smq coalesced + hi/lo out; k_merge new.

typedef unsigned short u16;
typedef unsigned int u32;
typedef __bf16 bf16x8 __attribute__((ext_vector_type(8)));
typedef float f32x4 __attribute__((ext_vector_type(4)));

typedef const __attribute__((address_space(1))) void* gas_t;
typedef __attribute__((address_space(3))) void* las_t;
__device__ __forceinline__ void gll16(const void* g, void* l) {
    __builtin_amdgcn_global_load_lds((gas_t)g, (las_t)l, 16, 0, 0);
}

__device__ inline float bf2f(u16 v) { union { u32 i; float f; } u; u.i = ((u32)v) << 16; return u.f; }
__device__ inline u16 f2bf(float f) {
    union { float f; u32 i; } u; u.f = f;
    u32 r = (u.i + 0x7fffu + ((u.i >> 16) & 1u)) >> 16;   // RNE
    return (u16)r;
}
__device__ inline void split2(float v, u16& h, u16& l) {
    h = f2bf(v);
    l = f2bf(v - bf2f(h));
}

// ------------------------------------------------- cvt weights to hi/lo pairs
__global__ void k_cvt_w(const float* __restrict__ Wq, const float* __restrict__ Wk,
                        const float* __restrict__ Wv, const float* __restrict__ Wg,
                        const float* __restrict__ Wo,
                        u16* __restrict__ Wh, u16* __restrict__ Wl,
                        u16* __restrict__ Woh, u16* __restrict__ Wol)
{
    int idx = blockIdx.x * 256 + threadIdx.x;
    if (idx < 524288) {                       // W_all[2048][256] = [q;k;v;g]
        int o = idx >> 8, c = idx & 255;
        int which = o >> 9, r = o & 511;
        const float* s = (which == 0) ? Wq : (which == 1) ? Wk : (which == 2) ? Wv : Wg;
        u16 h, l; split2(s[r * 256 + c], h, l);
        Wh[idx] = h; Wl[idx] = l;
    } else {
        int j = idx - 524288;                 // Wo[256][512]
        if (j < 131072) { u16 h, l; split2(Wo[j], h, l); Woh[j] = h; Wol[j] = l; }
    }
}

// ----------------------- cvt x -> xh/xl [bf_local][n][c] bf16 pairs (chunked)
__global__ __launch_bounds__(256) void k_cvt_x(const float* __restrict__ x,
                                               u16* __restrict__ xh, u16* __restrict__ xl,
                                               int c0)
{
    __shared__ __align__(16) u16 tileh[64 * 132];
    __shared__ __align__(16) u16 tilel[64 * 132];
    const int t = threadIdx.x;
    const int bfl = blockIdx.y;
    const int bfg = c0 + bfl;
    const int n0 = blockIdx.x * 128;
    const int b_ = bfg >> 4, f_ = bfg & 15;
    for (int s = 0; s < 2; ++s) {
        for (int ch2 = 0; ch2 < 2; ++ch2) {
            __syncthreads();
            for (int p = 0; p < 8; ++p) {
                int cl = p * 16 + (t >> 4);
                int c = ch2 * 128 + cl;
                const float* sp = x + (((size_t)b_ * 256 + c) * 16 + f_) * 4096
                                    + n0 + s * 64 + (t & 15) * 4;
                float4 v = *(const float4*)sp;
                float vv[4] = { v.x, v.y, v.z, v.w };
#pragma unroll
                for (int j = 0; j < 4; ++j) {
                    int nl = (t & 15) * 4 + j;
                    u16 h, l; split2(vv[j], h, l);
                    tileh[nl * 132 + cl] = h;
                    tilel[nl * 132 + cl] = l;
                }
            }
            __syncthreads();
#pragma unroll
            for (int i = 0; i < 4; ++i) {
                int flat = t + i * 256;
                int nn = flat >> 4, cc = flat & 15;
                size_t off = ((size_t)bfl * 4096 + n0 + s * 64 + nn) * 256 + ch2 * 128 + cc * 8;
                *(uint4*)(xh + off) = *(const uint4*)(tileh + nn * 132 + cc * 8);
                *(uint4*)(xl + off) = *(const uint4*)(tilel + nn * 132 + cc * 8);
            }
        }
    }
}

// ---------------------------------------- fused projection (single dispatch)
// my 0-3: q -> qf f32 [n][512] pixel-major; 4-7: k softmax-w -> kh/kl;
// 8-11: v -> vh/vl; 12-15: g sigmoid(+bg) -> gf f32 [ch][n].
__global__ __launch_bounds__(256) void k_proj(
    const u16* __restrict__ Wh, const u16* __restrict__ Wl,
    const u16* __restrict__ xh, const u16* __restrict__ xl,
    const float* __restrict__ bg,
    float* __restrict__ qf,
    u16* __restrict__ kh, u16* __restrict__ kl,
    u16* __restrict__ vh, u16* __restrict__ vl,
    float* __restrict__ gf)
{
    __shared__ __align__(16) char smem[65536];
    u16* Ah = (u16*)smem;                 // [128][64] each; linear LDS,
    u16* Al = (u16*)(smem + 16384);       // source pre-swizzled (chunk^row&7)
    u16* Bh = (u16*)(smem + 32768);
    u16* Bl = (u16*)(smem + 49152);
    float* Csh = (float*)smem;            // [128][69] f32, reused after K loop
    const int t = threadIdx.x;
    const int bfl = blockIdx.z;
    const int by = blockIdx.y;
    const int m0 = (by < 4) ? by * 128 : 512 + (by - 4) * 128;
    const int n0 = blockIdx.x * 128;
    const int lane = t & 63, wv = t >> 6, wm = wv >> 1, wn = wv & 1;
    f32x4 acc[4][4] = {};
    const u16* Aph = Wh + (size_t)m0 * 256;
    const u16* Apl = Wl + (size_t)m0 * 256;
    const u16* Bph = xh + ((size_t)bfl * 4096 + n0) * 256;
    const u16* Bpl = xl + ((size_t)bfl * 4096 + n0) * 256;

    for (int kt = 0; kt < 4; ++kt) {
        const int k0 = kt * 64;
#pragma unroll
        for (int jj = 0; jj < 4; ++jj) {
            int s = wv * 4 + jj;
            int row = s * 8 + (lane >> 3);
            int csrc = (lane & 7) ^ (row & 7);
            size_t go = (size_t)row * 256 + k0 + csrc * 8;
            gll16(Aph + go, Ah + s * 512);
            gll16(Apl + go, Al + s * 512);
            gll16(Bph + go, Bh + s * 512);
            gll16(Bpl + go, Bl + s * 512);
        }
        __syncthreads();
#pragma unroll
        for (int kk = 0; kk < 2; ++kk) {
            bf16x8 afh[4], afl[4], bfh[4], bfl_[4];
#pragma unroll
            for (int i = 0; i < 4; ++i) {
                int ra = wm * 64 + i * 16 + (lane & 15);
                int ca = ((kk * 4 + (lane >> 4)) ^ (ra & 7)) * 8;
                afh[i] = *(const bf16x8*)(Ah + ra * 64 + ca);
                afl[i] = *(const bf16x8*)(Al + ra * 64 + ca);
                int rb = wn * 64 + i * 16 + (lane & 15);
                int cb = ((kk * 4 + (lane >> 4)) ^ (rb & 7)) * 8;
                bfh[i] = *(const bf16x8*)(Bh + rb * 64 + cb);
                bfl_[i] = *(const bf16x8*)(Bl + rb * 64 + cb);
            }
#pragma unroll
            for (int mi = 0; mi < 4; ++mi)
#pragma unroll
                for (int ni = 0; ni < 4; ++ni) {
                    acc[mi][ni] = __builtin_amdgcn_mfma_f32_16x16x32_bf16(afh[mi], bfh[ni], acc[mi][ni], 0, 0, 0);
                    acc[mi][ni] = __builtin_amdgcn_mfma_f32_16x16x32_bf16(afh[mi], bfl_[ni], acc[mi][ni], 0, 0, 0);
                    acc[mi][ni] = __builtin_amdgcn_mfma_f32_16x16x32_bf16(afl[mi], bfh[ni], acc[mi][ni], 0, 0, 0);
                }
        }
        __syncthreads();
    }

    const int sector = m0 >> 9;               // 0:q 1:k 2:v 3:g
    for (int ph = 0; ph < 2; ++ph) {
        if (wn == ph) {
#pragma unroll
            for (int mi = 0; mi < 4; ++mi)
#pragma unroll
                for (int ni = 0; ni < 4; ++ni)
#pragma unroll
                    for (int r = 0; r < 4; ++r) {
                        int gr = wm * 64 + mi * 16 + (lane >> 4) * 4 + r;
                        int gcl = ni * 16 + (lane & 15);
                        Csh[gr * 69 + gcl] = acc[mi][ni][r];
                    }
        }
        __syncthreads();
        if (sector == 0) {                    // q: pixel-major f32 [n][512]
#pragma unroll
            for (int rr = 0; rr < 2; ++rr) {
                int n_loc = rr * 32 + (t >> 3);
                int oct = t & 7;
                float* dst = qf + ((size_t)bfl * 4096 + n0 + ph * 64 + n_loc) * 512 + m0;
#pragma unroll
                for (int j = 0; j < 4; ++j) {
                    f32x4 o;
#pragma unroll
                    for (int c = 0; c < 4; ++c)
                        o[c] = Csh[(j * 32 + oct * 4 + c) * 69 + n_loc];
                    *(f32x4*)(dst + j * 32 + oct * 4) = o;
                }
            }
        } else if (t < 128) {
            const float* src = Csh + t * 69;
            const int oloc = (m0 & 511) + t;
            const size_t doff = ((size_t)bfl * 512 + oloc) * 4096 + n0 + ph * 64;
            if (sector == 2) {                // v split pair
#pragma unroll
                for (int i = 0; i < 8; ++i) {
                    union { u16 h[8]; uint4 u; } ph_, pl_;
#pragma unroll
                    for (int j = 0; j < 8; ++j) split2(src[i * 8 + j], ph_.h[j], pl_.h[j]);
                    *(uint4*)(vh + doff + i * 8) = ph_.u;
                    *(uint4*)(vl + doff + i * 8) = pl_.u;
                }
            } else if (sector == 1) {         // k: softmax over the 64-px w row
                float mx = -3.0e38f;
                for (int j = 0; j < 64; ++j) mx = fmaxf(mx, src[j]);
                float sum = 0.f;
                for (int j = 0; j < 64; ++j) sum += expf(src[j] - mx);
                float rs = 1.0f / sum;
#pragma unroll
                for (int i = 0; i < 8; ++i) {
                    union { u16 h[8]; uint4 u; } ph_, pl_;
#pragma unroll
                    for (int j = 0; j < 8; ++j) {
                        float p = expf(src[i * 8 + j] - mx) * rs;
                        split2(p, ph_.h[j], pl_.h[j]);
                    }
                    *(uint4*)(kh + doff + i * 8) = ph_.u;
                    *(uint4*)(kl + doff + i * 8) = pl_.u;
                }
            } else {                          // g: sigmoid(x + bg) f32 [ch][n]
                float bgv = bg[oloc];
#pragma unroll
                for (int i = 0; i < 16; ++i) {
                    float4 o;
                    float* po = (float*)&o;
#pragma unroll
                    for (int j = 0; j < 4; ++j)
                        po[j] = 1.0f / (1.0f + expf(-(src[i * 4 + j] + bgv)));
                    *(float4*)(gf + doff + i * 4) = o;
                }
            }
        }
        __syncthreads();
    }
}

// ---------------- q softmax over h; outputs hi/lo bf16 [bh][n][64] frag-ready
__global__ __launch_bounds__(256) void k_smq(
    const float* __restrict__ qf, u16* __restrict__ qTh, u16* __restrict__ qTl)
{
    __shared__ float S[4 * 64 * 64];       // [w][h][d]
    const int t = threadIdx.x;
    const int wblk = blockIdx.x;           // 0..15
    const int bh = blockIdx.y;
    const int bfl = bh >> 3, head = bh & 7;
    const float* qbase = qf + (size_t)bfl * 4096 * 512 + head * 64;
#pragma unroll
    for (int r = 0; r < 16; ++r) {
        int h = r * 4 + (t >> 6);
        int w = (t >> 4) & 3;
        int li = t & 15;
        f32x4 v = *(const f32x4*)(qbase + (size_t)(h * 64 + wblk * 4 + w) * 512 + li * 4);
        *(f32x4*)(S + ((w * 64 + h) * 64 + li * 4)) = v;
    }
    __syncthreads();
    {
        int w = t >> 6, d = t & 63;
        float mx = -3.0e38f;
        for (int h = 0; h < 64; ++h) mx = fmaxf(mx, S[(w * 64 + h) * 64 + d]);
        float sum = 0.f;
        for (int h = 0; h < 64; ++h) {
            int i = (w * 64 + h) * 64 + d;
            float e = expf(S[i] - mx);
            S[i] = e;
            sum += e;
        }
        float rs = 1.0f / sum;
        for (int h = 0; h < 64; ++h) S[(w * 64 + h) * 64 + d] *= rs;
    }
    __syncthreads();
#pragma unroll
    for (int r = 0; r < 8; ++r) {
        int px = r * 32 + (t >> 3);
        int h = px >> 2, w = px & 3;
        int oct = t & 7;
        union { u16 h16[8]; uint4 u; } ph_, pl_;
#pragma unroll
        for (int j = 0; j < 8; ++j)
            split2(S[(w * 64 + h) * 64 + oct * 8 + j], ph_.h16[j], pl_.h16[j]);
        size_t off = ((size_t)bh * 4096 + h * 64 + wblk * 4 + w) * 64 + oct * 8;
        *(uint4*)(qTh + off) = ph_.u;
        *(uint4*)(qTl + off) = pl_.u;
    }
}

// ---- per (octant, bh): kv,vsum,ksum partials over 512 px (ones-row trick)
__global__ __launch_bounds__(256) void k_kv(
    const u16* __restrict__ kh, const u16* __restrict__ kl,
    const u16* __restrict__ vh, const u16* __restrict__ vl,
    float* __restrict__ kvp, float* __restrict__ vsp, float* __restrict__ ksp)
{
    __shared__ __align__(16) char smem[65536];
    u16* Kh = (u16*)smem;
    u16* Kl = (u16*)(smem + 16384);
    u16* Vh = (u16*)(smem + 32768);
    u16* Vl = (u16*)(smem + 49152);
    float* mrg = (float*)smem;
    const int t = threadIdx.x;
    const int oct = blockIdx.x;
    const int bh = blockIdx.y;
    const int NBH = gridDim.y;
    const int lane = t & 63, wv = t >> 6;
    const size_t hb = (size_t)bh * 64 * 4096;

    f32x4 acc[5][5] = {};
    bf16x8 ones;
#pragma unroll
    for (int j = 0; j < 8; ++j) ones[j] = (lane & 15) == 0 ? (__bf16)1.0f : (__bf16)0.0f;

    for (int cc = 0; cc < 4; ++cc) {
        const int pxc = oct * 512 + cc * 128;
#pragma unroll
        for (int jj = 0; jj < 4; ++jj) {
            int s = wv * 4 + jj;
            int row = s * 4 + (lane >> 4);
            int csrc = (lane & 15) ^ (row & 7);
            size_t go = hb + (size_t)row * 4096 + pxc + csrc * 8;
            gll16(kh + go, Kh + s * 512);
            gll16(kl + go, Kl + s * 512);
            gll16(vh + go, Vh + s * 512);
            gll16(vl + go, Vl + s * 512);
        }
        __syncthreads();
        bf16x8 ah[4], al[4], bh_[4], bl_[4];
#pragma unroll
        for (int i = 0; i < 4; ++i) {
            int ra = i * 16 + (lane & 15);
            int kc = (wv * 4 + (lane >> 4)) ^ (ra & 7);
            int off = ra * 128 + kc * 8;
            ah[i]  = *(const bf16x8*)(Kh + off);
            al[i]  = *(const bf16x8*)(Kl + off);
            bh_[i] = *(const bf16x8*)(Vh + off);
            bl_[i] = *(const bf16x8*)(Vl + off);
        }
#pragma unroll
        for (int di = 0; di < 5; ++di) {
            bf16x8 a = (di < 4) ? ah[di] : ones;
#pragma unroll
            for (int ei = 0; ei < 5; ++ei) {
                bf16x8 b = (ei < 4) ? bh_[ei] : ones;
                acc[di][ei] = __builtin_amdgcn_mfma_f32_16x16x32_bf16(a, b, acc[di][ei], 0, 0, 0);
            }
        }
#pragma unroll
        for (int di = 0; di < 5; ++di) {
            bf16x8 a = (di < 4) ? ah[di] : ones;
#pragma unroll
            for (int ei = 0; ei < 4; ++ei)
                acc[di][ei] = __builtin_amdgcn_mfma_f32_16x16x32_bf16(a, bl_[ei], acc[di][ei], 0, 0, 0);
        }
#pragma unroll
        for (int di = 0; di < 4; ++di)
#pragma unroll
            for (int ei = 0; ei < 5; ++ei) {
                bf16x8 b = (ei < 4) ? bh_[ei] : ones;
                acc[di][ei] = __builtin_amdgcn_mfma_f32_16x16x32_bf16(al[di], b, acc[di][ei], 0, 0, 0);
            }
        __syncthreads();
    }

    float* kvm = mrg;
    float* vsm = mrg + 64 * 68;
    float* ksm = mrg + 64 * 68 + 64;
    for (int i = t; i < 64 * 68 + 128; i += 256) mrg[i] = 0.f;
    __syncthreads();
#pragma unroll
    for (int di = 0; di < 4; ++di)
#pragma unroll
        for (int ei = 0; ei < 4; ++ei)
#pragma unroll
            for (int r = 0; r < 4; ++r) {
                int d = di * 16 + (lane >> 4) * 4 + r;
                int e = ei * 16 + (lane & 15);
                atomicAdd(&kvm[d * 68 + e], acc[di][ei][r]);
            }
    if (lane < 16) {
#pragma unroll
        for (int ei = 0; ei < 4; ++ei) atomicAdd(&vsm[ei * 16 + lane], acc[4][ei][0]);
    }
    if ((lane & 15) == 0) {
#pragma unroll
        for (int di = 0; di < 4; ++di)
#pragma unroll
            for (int r = 0; r < 4; ++r)
                atomicAdd(&ksm[di * 16 + (lane >> 4) * 4 + r], acc[di][4][r]);
    }
    __syncthreads();
    float* op = kvp + ((size_t)oct * NBH + bh) * 4096;
#pragma unroll
    for (int i = 0; i < 16; ++i) {
        int idx = t + i * 256;
        op[idx] = kvm[(idx >> 6) * 68 + (idx & 63)];
    }
    if (t < 64) {
        vsp[((size_t)oct * NBH + bh) * 64 + t] = vsm[t];
        ksp[((size_t)oct * NBH + bh) * 64 + t] = 512.0f + ksm[t];
    }
}

// --- merge octants -> kvT_aug [bh][80 m][64 k] hi/lo (row64=ksl) + aux(csl,kstp)
__global__ __launch_bounds__(256) void k_merge(
    const float* __restrict__ kvp, const float* __restrict__ vsp,
    const float* __restrict__ ksp,
    u16* __restrict__ kvTh, u16* __restrict__ kvTl,
    float* __restrict__ aux, int NBH)
{
    __shared__ float kv[64 * 68];
    __shared__ float vsl[64];
    __shared__ float kslL[64];
    const int t = threadIdx.x;
    const int bh = blockIdx.x;
#pragma unroll
    for (int i = 0; i < 16; ++i) {
        int idx = t + i * 256;
        float s = 0.f;
#pragma unroll
        for (int o = 0; o < 8; ++o) s += kvp[((size_t)o * NBH + bh) * 4096 + idx];
        kv[(idx >> 6) * 68 + (idx & 63)] = s;
    }
    if (t < 64) {
        float a = 0.f, b = 0.f;
#pragma unroll
        for (int o = 0; o < 8; ++o) {
            a += vsp[((size_t)o * NBH + bh) * 64 + t];
            b += ksp[((size_t)o * NBH + bh) * 64 + t];
        }
        vsl[t] = a; kslL[t] = b;
    }
    __syncthreads();
    if (t < 64) {                              // csl[e] = sum_d kv_full[d][e]
        float s = 0.f;
        for (int d = 0; d < 64; ++d) s += kv[d * 68 + t];
        aux[(size_t)bh * 68 + t] = s + 64.0f * vsl[t];
    }
    if (t == 64) {                             // kstp = sum_d ksl[d]
        float s = 0.f;
        for (int d = 0; d < 64; ++d) s += kslL[d];
        aux[(size_t)bh * 68 + 64] = s;
    }
    __syncthreads();
    {   // rows 0..63: kvT[m][k] = kv[k][m] + vsl[m]
        int m = t >> 2, kq = t & 3;
        union { u16 h[16]; uint4 u[2]; } hh, ll;
        float vm = vsl[m];
#pragma unroll
        for (int i = 0; i < 16; ++i) {
            int k = kq * 16 + i;
            split2(kv[k * 68 + m] + vm, hh.h[i], ll.h[i]);
        }
        size_t off = (size_t)bh * 5120 + (size_t)m * 64 + kq * 16;
        *(uint4*)(kvTh + off) = hh.u[0];
        *(uint4*)(kvTh + off + 8) = hh.u[1];
        *(uint4*)(kvTl + off) = ll.u[0];
        *(uint4*)(kvTl + off + 8) = ll.u[1];
    }
    if (t < 64) {   // rows 64..79: 64=ksl, 65..79=0
        int m2 = 64 + (t >> 2), kq = t & 3;
        union { u16 h[16]; uint4 u[2]; } hh, ll;
#pragma unroll
        for (int i = 0; i < 16; ++i) {
            float v = (m2 == 64) ? kslL[kq * 16 + i] : 0.f;
            split2(v, hh.h[i], ll.h[i]);
        }
        size_t off = (size_t)bh * 5120 + (size_t)m2 * 64 + kq * 16;
        *(uint4*)(kvTh + off) = hh.u[0];
        *(uint4*)(kvTh + off + 8) = hh.u[1];
        *(uint4*)(kvTl + off) = ll.u[0];
        *(uint4*)(kvTl + off + 8) = ll.u[1];
    }
}

// -------- attention via MFMA: D[e][n] = kvT x p (3-pass); epilogue gate+store
__global__ __launch_bounds__(256) void k_att(
    const u16* __restrict__ qTh_g, const u16* __restrict__ qTl_g,
    const float* __restrict__ gf,
    const u16* __restrict__ kvTh_g, const u16* __restrict__ kvTl_g,
    const float* __restrict__ aux,
    u16* __restrict__ atth, u16* __restrict__ attl)
{
    __shared__ __align__(16) char smem[71680];
    u16* qh_s = (u16*)smem;                // [256 n][64 d], chunk-swizzled
    u16* ql_s = (u16*)(smem + 32768);
    u16* ah_s = (u16*)smem;                // att out [256 n][68 e] (reuse)
    u16* al_s = (u16*)(smem + 34816);
    float* szl = (float*)(smem + 69632);   // [256]
    float* cslL = (float*)(smem + 70656);  // [65]
    const int t = threadIdx.x;
    const int lane = t & 63, wv = t >> 6;
    const int row = lane & 15, oct = lane >> 4;
    const int bh = blockIdx.y;
    const int bfl = bh >> 3, head = bh & 7;
    const int n0 = blockIdx.x * 256;

    const u16* qhb = qTh_g + ((size_t)bh * 4096 + n0) * 64;
    const u16* qlb = qTl_g + ((size_t)bh * 4096 + n0) * 64;
#pragma unroll
    for (int r = 0; r < 8; ++r) {
        int chunk = r * 256 + t;
        int n = chunk >> 3, c = chunk & 7;
        size_t src = (size_t)n * 64 + (size_t)((c ^ (n & 7)) * 8);
        gll16(qhb + src, qh_s + r * 2048 + wv * 512);
        gll16(qlb + src, ql_s + r * 2048 + wv * 512);
    }
    if (t < 65) cslL[t] = aux[(size_t)bh * 68 + t];
    __syncthreads();

    f32x4 acc[5][4] = {};
    const u16* Ahg = kvTh_g + (size_t)bh * 5120;
    const u16* Alg = kvTl_g + (size_t)bh * 5120;
#pragma unroll
    for (int pass = 0; pass < 3; ++pass) {
        const u16* Ap = (pass == 2) ? Alg : Ahg;
        const u16* Bp = (pass == 1) ? ql_s : qh_s;
#pragma unroll
        for (int ks = 0; ks < 2; ++ks) {
            bf16x8 af[5], bq[4];
#pragma unroll
            for (int mi = 0; mi < 5; ++mi)
                af[mi] = *(const bf16x8*)(Ap + (size_t)(mi * 16 + row) * 64 + ks * 32 + oct * 8);
#pragma unroll
            for (int ni = 0; ni < 4; ++ni) {
                int n_loc = wv * 64 + ni * 16 + row;
                int chs = ((ks * 4 + oct) ^ (n_loc & 7)) * 8;
                bq[ni] = *(const bf16x8*)(Bp + n_loc * 64 + chs);
            }
#pragma unroll
            for (int mi = 0; mi < 5; ++mi)
#pragma unroll
                for (int ni = 0; ni < 4; ++ni)
                    acc[mi][ni] = __builtin_amdgcn_mfma_f32_16x16x32_bf16(af[mi], bq[ni], acc[mi][ni], 0, 0, 0);
        }
    }
    if (oct == 0) {                        // row 64 = Sum_d ksl[d] p[n][d]
#pragma unroll
        for (int ni = 0; ni < 4; ++ni)
            szl[wv * 64 + ni * 16 + row] = acc[4][ni][0];
    }
    __syncthreads();                       // qT region now reusable

    const float kstp = cslL[64];
#pragma unroll
    for (int ni = 0; ni < 4; ++ni) {
        int n_loc = wv * 64 + ni * 16 + row;
        int n_g = n0 + n_loc;
        float zz = 0.125f / fmaxf(szl[n_loc] + kstp, 1e-6f);
#pragma unroll
        for (int mi = 0; mi < 4; ++mi) {
            int e0 = mi * 16 + oct * 4;
            u16 hh[4], ll2[4];
#pragma unroll
            for (int r2 = 0; r2 < 4; ++r2) {
                int e = e0 + r2;
                float g = gf[((size_t)bfl * 512 + head * 64 + e) * 4096 + n_g];
                float val = (acc[mi][ni][r2] + cslL[e]) * zz * g;
                split2(val, hh[r2], ll2[r2]);
            }
            *(u32*)(ah_s + n_loc * 68 + e0)     = (u32)hh[0] | ((u32)hh[1] << 16);
            *(u32*)(ah_s + n_loc * 68 + e0 + 2) = (u32)hh[2] | ((u32)hh[3] << 16);
            *(u32*)(al_s + n_loc * 68 + e0)     = (u32)ll2[0] | ((u32)ll2[1] << 16);
            *(u32*)(al_s + n_loc * 68 + e0 + 2) = (u32)ll2[2] | ((u32)ll2[3] << 16);
        }
    }
    __syncthreads();
    u16* gh = atth + ((size_t)bfl * 4096 + n0) * 512 + head * 64;
    u16* gl = attl + ((size_t)bfl * 4096 + n0) * 512 + head * 64;
#pragma unroll
    for (int r = 0; r < 16; ++r) {
        int n_loc = r * 16 + (t >> 4);
        int u2 = t & 15;
        *(uint2*)(gh + (size_t)n_loc * 512 + u2 * 4) = *(const uint2*)(ah_s + n_loc * 68 + u2 * 4);
        *(uint2*)(gl + (size_t)n_loc * 512 + u2 * 4) = *(const uint2*)(al_s + n_loc * 68 + u2 * 4);
    }
}

// --------------------------------- out = Wo x att + bo, f32, (b,c,f,h,w) layout
__global__ __launch_bounds__(256) void k_out(
    const u16* __restrict__ Woh, const u16* __restrict__ Wol,
    const u16* __restrict__ atth, const u16* __restrict__ attl,
    const float* __restrict__ bo, float* __restrict__ out, int c0)
{
    __shared__ __align__(16) u16 smem[32768];
    u16* Ah = smem;
    u16* Al = smem + 8192;
    u16* Bh = smem + 16384;
    u16* Bl = smem + 24576;
    const int t = threadIdx.x;
    const int bfl = blockIdx.z;
    const int bfg = c0 + bfl;
    const int m0 = blockIdx.y * 128;
    const int n0 = blockIdx.x * 128;
    const int lane = t & 63, wv = t >> 6, wm = wv >> 1, wn = wv & 1;
    f32x4 acc[4][4] = {};
    const u16* Aph = Woh + (size_t)m0 * 512;
    const u16* Apl = Wol + (size_t)m0 * 512;
    const u16* Bph = atth + ((size_t)bfl * 4096 + n0) * 512;
    const u16* Bpl = attl + ((size_t)bfl * 4096 + n0) * 512;
    for (int kt = 0; kt < 8; ++kt) {
        const int k0 = kt * 64;
#pragma unroll
        for (int jj = 0; jj < 4; ++jj) {
            int s = wv * 4 + jj;
            int row = s * 8 + (lane >> 3);
            int csrc = (lane & 7) ^ (row & 7);
            size_t go = (size_t)row * 512 + k0 + csrc * 8;
            gll16(Aph + go, Ah + s * 512);
            gll16(Apl + go, Al + s * 512);
            gll16(Bph + go, Bh + s * 512);
            gll16(Bpl + go, Bl + s * 512);
        }
        __syncthreads();
#pragma unroll
        for (int kk = 0; kk < 2; ++kk) {
            bf16x8 afh[4], afl[4], bfh[4], bfl_[4];
#pragma unroll
            for (int i = 0; i < 4; ++i) {
                int ra = wm * 64 + i * 16 + (lane & 15);
                int ca = ((kk * 4 + (lane >> 4)) ^ (ra & 7)) * 8;
                afh[i] = *(const bf16x8*)(Ah + ra * 64 + ca);
                afl[i] = *(const bf16x8*)(Al + ra * 64 + ca);
                int rb = wn * 64 + i * 16 + (lane & 15);
                int cb = ((kk * 4 + (lane >> 4)) ^ (rb & 7)) * 8;
                bfh[i] = *(const bf16x8*)(Bh + rb * 64 + cb);
                bfl_[i] = *(const bf16x8*)(Bl + rb * 64 + cb);
            }
#pragma unroll
            for (int mi = 0; mi < 4; ++mi)
#pragma unroll
                for (int ni = 0; ni < 4; ++ni) {
                    acc[mi][ni] = __builtin_amdgcn_mfma_f32_16x16x32_bf16(afh[mi], bfh[ni], acc[mi][ni], 0, 0, 0);
                    acc[mi][ni] = __builtin_amdgcn_mfma_f32_16x16x32_bf16(afh[mi], bfl_[ni], acc[mi][ni], 0, 0, 0);
                    acc[mi][ni] = __builtin_amdgcn_mfma_f32_16x16x32_bf16(afl[mi], bfh[ni], acc[mi][ni], 0, 0, 0);
                }
        }
        __syncthreads();
    }
    const int b_ = bfg >> 4, f_ = bfg & 15;
#pragma unroll
    for (int mi = 0; mi < 4; ++mi)
#pragma unroll
        for (int ni = 0; ni < 4; ++ni)
#pragma unroll
            for (int r = 0; r < 4; ++r) {
                int o = m0 + wm * 64 + mi * 16 + (lane >> 4) * 4 + r;
                int nn = n0 + wn * 64 + ni * 16 + (lane & 15);
                out[(((size_t)b_ * 256 + o) * 16 + f_) * 4096 + nn] = acc[mi][ni][r] + bo[o];
            }
}

extern "C" void kernel_launch(void* const* d_in, const int* in_sizes, int n_in,
                              void* d_out, int out_size, void* d_ws, size_t ws_size,
                              hipStream_t stream)
{
    const float* x  = (const float*)d_in[0];
    const float* Wq = (const float*)d_in[1];
    const float* Wk = (const float*)d_in[2];
    const float* Wv = (const float*)d_in[3];
    const float* Wg = (const float*)d_in[4];
    const float* bg = (const float*)d_in[5];
    const float* Wo = (const float*)d_in[6];
    const float* bo = (const float*)d_in[7];
    float* out = (float*)d_out;
    char* ws = (char*)d_ws;

    const size_t PER_BF = 47386624ull;
    const size_t FIXED  = 2621440ull;
    int CH = 32;
    while (CH > 1 && FIXED + (size_t)CH * PER_BF > ws_size) CH >>= 1;
    const int nch = 32 / CH;

    u16* Wh  = (u16*)(ws);
    u16* Wl  = (u16*)(ws + 1048576);
    u16* Woh = (u16*)(ws + 2097152);
    u16* Wol = (u16*)(ws + 2359296);
    char* dyn = ws + FIXED;
    u16*   xh   = (u16*)(dyn);
    u16*   xl   = (u16*)(dyn + (size_t)CH * 2097152);
    u16*   kh   = (u16*)(dyn + (size_t)CH * 4194304);    // att hi aliases after k_kv
    u16*   kl   = (u16*)(dyn + (size_t)CH * 8388608);    // att lo aliases after k_kv
    u16*   vh   = (u16*)(dyn + (size_t)CH * 12582912);
    u16*   vl   = (u16*)(dyn + (size_t)CH * 16777216);
    float* qf   = (float*)(dyn + (size_t)CH * 20971520);
    float* gf   = (float*)(dyn + (size_t)CH * 29360128);
    u16*   qTh  = (u16*)(dyn + (size_t)CH * 37748736);
    u16*   qTl  = (u16*)(dyn + (size_t)CH * 41943040);
    float* kvp  = (float*)(dyn + (size_t)CH * 46137344);
    float* vsp  = (float*)(dyn + (size_t)CH * 47185920);
    float* ksp  = (float*)(dyn + (size_t)CH * 47202304);
    u16*   kvTh = (u16*)(dyn + (size_t)CH * 47218688);
    u16*   kvTl = (u16*)(dyn + (size_t)CH * 47300608);
    float* aux  = (float*)(dyn + (size_t)CH * 47382528);
    u16*   atth = kh;
    u16*   attl = kl;

    k_cvt_w<<<dim3(2560), dim3(256), 0, stream>>>(Wq, Wk, Wv, Wg, Wo, Wh, Wl, Woh, Wol);

    for (int c = 0; c < nch; ++c) {
        const int c0 = c * CH;
        k_cvt_x<<<dim3(32, CH),     dim3(256), 0, stream>>>(x, xh, xl, c0);
        k_proj <<<dim3(32, 16, CH), dim3(256), 0, stream>>>(Wh, Wl, xh, xl, bg,
                                                            qf, kh, kl, vh, vl, gf);
        k_kv   <<<dim3(8, CH * 8),  dim3(256), 0, stream>>>(kh, kl, vh, vl, kvp, vsp, ksp);
        k_merge<<<dim3(CH * 8),     dim3(256), 0, stream>>>(kvp, vsp, ksp, kvTh, kvTl, aux, CH * 8);
        k_smq  <<<dim3(16, CH * 8), dim3(256), 0, stream>>>(qf, qTh, qTl);
        k_att  <<<dim3(16, CH * 8), dim3(256), 0, stream>>>(qTh, qTl, gf, kvTh, kvTl, aux, atth, attl);
        k_out  <<<dim3(32, 2, CH),  dim3(256), 0, stream>>>(Woh, Wol, atth, attl, bo, out, c0);
    }
}